// Round 7
// baseline (336.502 us; speedup 1.0000x reference)
//
#include <hip/hip_runtime.h>
#include <cstdint>

using u64 = unsigned long long;
using u32 = unsigned int;

// ---------------------------------------------------------------------------
// Fused prep: BN constants + exact integer thresholds (layers 2-4) + packing.
// ---------------------------------------------------------------------------
struct PrepArgs {
  const float* bng[5]; const float* bnb[5]; const float* bnm[5]; const float* bnv[5];
  float* inv1; float* cc1; float* inv5; float* cc5;
  int* thr[3]; int* flp[3];
  const float* w[4];
  u64* wp[4]; u64* wz[4];
  u32* flags;
};

__global__ __launch_bounds__(256) void prep_all(PrepArgs a) {
  int i = blockIdx.x * 256 + threadIdx.x;
  if (i < 704) {
    const int off[6] = {0, 64, 192, 320, 512, 704};
    int l = 0;
    while (i >= off[l + 1]) ++l;
    int c = i - off[l];
    float iv = __fdiv_rn(a.bng[l][c], __fsqrt_rn(__fadd_rn(a.bnv[l][c], 1e-5f)));
    float cb = __fsub_rn(a.bnb[l][c], __fmul_rn(a.bnm[l][c], iv));
    if (l == 0) { a.inv1[c] = iv; a.cc1[c] = cb; }
    else if (l == 4) { a.inv5[c] = iv; a.cc5[c] = cb; }
    else {
      auto pred = [&](int v_) {
        return __fadd_rn(__fmul_rn((float)v_, iv), cb) > 0.f;
      };
      int Tx, fl;
      if (iv == 0.f) { Tx = pred(0) ? -100000 : 100000; fl = 0; }
      else if (iv > 0.f) {
        if (pred(-2048)) { Tx = -100000; fl = 0; }
        else if (!pred(2048)) { Tx = 100000; fl = 0; }
        else {
          int lo = -2048, hi = 2048;
          while (hi - lo > 1) { int md = (lo + hi) >> 1; if (pred(md)) hi = md; else lo = md; }
          Tx = hi; fl = 0;
        }
      } else {
        if (pred(2048)) { Tx = -100000; fl = -1; }
        else if (!pred(-2048)) { Tx = 100000; fl = -1; }
        else {
          int lo = -2048, hi = 2048;
          while (hi - lo > 1) { int md = (lo + hi) >> 1; if (pred(md)) lo = md; else hi = md; }
          Tx = lo ^ -1; fl = -1;
        }
      }
      a.thr[l - 1][c] = Tx; a.flp[l - 1][c] = fl;
    }
    return;
  }
  int j = i - 704;
  if (j >= 7488) return;
  const int poff[5] = {0, 1152, 3456, 6912, 7488};
  const int ICt[4] = {64, 128, 128, 192};
  const int Kt[4]  = {9, 9, 9, 1};
  const int Wt[4]  = {1, 2, 2, 3};
  int l = 0;
  while (j >= poff[l + 1]) ++l;
  int idx = j - poff[l];
  int W = Wt[l], K = Kt[l], IC = ICt[l];
  int wi = idx % W;
  int rest = idx / W;
  int t = rest % K;
  int oc = rest / K;
  u64 p = 0, z = 0;
  int icbase = wi * 64;
  int nb = IC - icbase; if (nb > 64) nb = 64;
  const float* w = a.w[l];
  for (int b = 0; b < nb; ++b) {
    float f = w[((size_t)oc * IC + (icbase + b)) * K + t];
    if (f > 0.f) p |= (1ull << b);
    else if (f == 0.f) z |= (1ull << b);
  }
  a.wp[l][idx] = p;
  a.wz[l][idx] = z;
  if (z) atomicOr(a.flags + l, 1u);
}

// ---------------------------------------------------------------------------
// Pad fp32 input into [n][130][136].
// ---------------------------------------------------------------------------
__global__ __launch_bounds__(256) void pad_x(const float* __restrict__ x,
                                             float* __restrict__ xpad) {
  int idx = blockIdx.x * 256 + threadIdx.x;
  int c = idx & 127, r = (idx >> 7) & 127, n = idx >> 14;
  xpad[((size_t)n * 130 + r + 1) * 136 + c + 1] = x[idx];
}

// ---------------------------------------------------------------------------
// conv1 (unchanged from R6): fp32 1->64ch 3x3 s2 + BN threshold -> padded pack.
// ---------------------------------------------------------------------------
__global__ __launch_bounds__(256) void conv1_bin(
    const float* __restrict__ xpad, const float* __restrict__ w1, const float* __restrict__ b1,
    const float* __restrict__ inv1, const float* __restrict__ cc1,
    u64* __restrict__ a1p) {
  int tid = threadIdx.x, lane = tid & 63;
  int rb = __builtin_amdgcn_readfirstlane(tid >> 6);
  int blk = blockIdx.x;
  int y = (blk % 16) * 4 + rb;
  int n = blk / 16;
  float W[9];
#pragma unroll
  for (int t = 0; t < 9; ++t) W[t] = w1[lane * 9 + t];
  float bias = b1[lane], iv = inv1[lane], cb = cc1[lane];
  const float* sb = xpad + ((size_t)n * 130 + 2 * y) * 136;
  float A[12], B[12], C[12];
  u64 rowm = 0;
  int xb = 0;

#define FLD(BUF, POFF)                                     \
  _Pragma("unroll") for (int _r = 0; _r < 3; ++_r)         \
  _Pragma("unroll") for (int _j = 0; _j < 4; ++_j)         \
    BUF[_r * 4 + _j] = sb[_r * 136 + (POFF) + _j];
#define FPX(XO, B0F, C0, B1F, C1, B2F, C2) {                          \
  float acc = 0.f;                                                    \
  _Pragma("unroll") for (int _r = 0; _r < 3; ++_r)                    \
    acc += B0F[_r * 4 + (C0)] * W[_r * 3 + 0]                         \
         + B1F[_r * 4 + (C1)] * W[_r * 3 + 1]                         \
         + B2F[_r * 4 + (C2)] * W[_r * 3 + 2];                        \
  float h = __fadd_rn(acc, bias);                                     \
  float bnv = __fadd_rn(__fmul_rn(h, iv), cb);                        \
  u64 _m = __ballot(bnv > 0.f);                                       \
  rowm = (lane == (XO)) ? _m : rowm; }
#define FSTEP(BA, BB, BC, POFF, XB)  \
  FLD(BC, (POFF) + 8);               \
  FPX((XB), BA, 0, BA, 1, BA, 2);    \
  FPX((XB) + 1, BA, 2, BA, 3, BB, 0);

  FLD(A, 0); FLD(B, 4);
  for (int g = 0; g < 10; ++g) {
    FSTEP(A, B, C, 0, xb);
    FSTEP(B, C, A, 4, xb + 2);
    FSTEP(C, A, B, 8, xb + 4);
    sb += 12; xb += 6;
  }
  FSTEP(A, B, C, 0, xb);
  FSTEP(B, C, A, 4, xb + 2);
  a1p[((size_t)n * 66 + (y + 1)) * 68 + lane + 1] = rowm;
#undef FLD
#undef FPX
#undef FSTEP
}

// ---------------------------------------------------------------------------
// pa precompute: window popcounts (oc-independent). lane = output px.
// OUT=64: 1 row/wave (4 rows/block); OUT=32: 2 rows/wave (8 rows/block).
// ---------------------------------------------------------------------------
template <int CINW, int STRIDE, int IN_HW, int OUT_HW>
__global__ __launch_bounds__(256) void pa_comp(const u64* __restrict__ ain,
                                               int* __restrict__ paout) {
  constexpr int IPW = IN_HW + 4;
  int tid = threadIdx.x, lane = tid & 63, wv = tid >> 6;
  int y, p, n;
  if (OUT_HW == 64) {
    p = lane;
    y = (blockIdx.x % 16) * 4 + wv;
    n = blockIdx.x / 16;
  } else {
    int h = lane >> 5; p = lane & 31;
    y = (blockIdx.x % 4) * 8 + wv * 2 + h;
    n = blockIdx.x / 4;
  }
  const u64* base = ain + (((size_t)n * (IN_HW + 2) + STRIDE * y) * IPW + STRIDE * p) * CINW;
  int s = 0;
#pragma unroll
  for (int r = 0; r < 3; ++r)
#pragma unroll
    for (int c = 0; c < 3; ++c)
#pragma unroll
      for (int w = 0; w < CINW; ++w)
        s += __popcll(base[((size_t)r * IPW + c) * CINW + w]);
  paout[((size_t)n * OUT_HW + y) * OUT_HW + p] = s;
}

// ---------------------------------------------------------------------------
// conv2: CINW=1, stride1, 64x64. SGPR batch ping-pong: 4 px / batch (6 cols),
// double-buffered; per batch: [anchored drain][issue next s_loads][compute].
// pa from pa2 array (batched with acts). lane = oc, weights in VGPRs.
// ---------------------------------------------------------------------------
template <int Z>
__device__ __forceinline__ u64 c2_row(const u64* sb, const u64* wvp_row, const u64* wvz_row,
                                      int Tx, int flip, int lane, const int* par_row) {
  u64 W[9];
#pragma unroll
  for (int t = 0; t < 9; ++t) W[t] = wvp_row[t];
  u64 rowm = 0;

  if (Z) {
    // cold path (never taken for this input): simple exact version
    for (int x = 0; x < 64; ++x) {
      int s = 0, z = 0;
      for (int r = 0; r < 3; ++r)
        for (int c = 0; c < 3; ++c) {
          u64 a = sb[r * 68 + x + c];
          s += __popcll(a & W[r * 3 + c]);
          z += __popcll(a & wvz_row[r * 3 + c]);
        }
      int val = 2 * s - par_row[x] + z;
      u64 m_ = __ballot((val ^ flip) >= Tx);
      rowm = (lane == x) ? m_ : rowm;
    }
    return rowm;
  }

  u64 A[18], B[18];
  int panA[4], panB[4];
#pragma unroll
  for (int r = 0; r < 3; ++r)
#pragma unroll
    for (int k = 0; k < 6; ++k) A[r * 6 + k] = sb[r * 68 + k];
#pragma unroll
  for (int k = 0; k < 4; ++k) panA[k] = par_row[k];

#define C2BODY(CUR, PAC, NXT, PAN, BI) {                                        \
  const u64* sbx = sb; const int* pax = par_row;                                \
  asm volatile("" : "+s"(sbx), "+s"(pax) : "s"(CUR[0]), "s"(PAC[0]));           \
  _Pragma("unroll") for (int r_ = 0; r_ < 3; ++r_)                              \
    _Pragma("unroll") for (int k_ = 0; k_ < 6; ++k_)                            \
      NXT[r_ * 6 + k_] = sbx[r_ * 68 + ((BI) + 1) * 4 + k_];                    \
  _Pragma("unroll") for (int k_ = 0; k_ < 4; ++k_)                              \
    PAN[k_] = pax[((BI) + 1) * 4 + k_];                                         \
  _Pragma("unroll") for (int j_ = 0; j_ < 4; ++j_) {                            \
    int s_ = 0;                                                                 \
    _Pragma("unroll") for (int r_ = 0; r_ < 3; ++r_)                            \
      _Pragma("unroll") for (int c_ = 0; c_ < 3; ++c_)                          \
        s_ += __popcll(CUR[r_ * 6 + j_ + c_] & W[r_ * 3 + c_]);                 \
    int val_ = 2 * s_ - PAC[j_];                                                \
    u64 m_ = __ballot((val_ ^ flip) >= Tx);                                     \
    rowm = (lane == ((BI) * 4 + j_)) ? m_ : rowm; } }

#pragma unroll 1
  for (int g = 0; g < 8; ++g) {
    C2BODY(A, panA, B, panB, 2 * g);      // g=7 issues batch-16 loads: harmless
    C2BODY(B, panB, A, panA, 2 * g + 1);  // in-bounds of workspace, unused
  }
#undef C2BODY
  return rowm;
}

__global__ __launch_bounds__(256) void bconv2(
    const u64* __restrict__ ain, const u64* __restrict__ wp, const u64* __restrict__ wz,
    const u32* __restrict__ flag, const int* __restrict__ thr, const int* __restrict__ flp,
    const int* __restrict__ pa2, u64* __restrict__ aout) {
  int tid = threadIdx.x, lane = tid & 63;
  int wv = __builtin_amdgcn_readfirstlane(tid >> 6);
  int ocw = wv & 1, rblk = wv >> 1;
  int blk = blockIdx.x;                 // 128*32
  int y = (blk % 32) * 2 + rblk;
  int n = blk / 32;
  int oc = ocw * 64 + lane;
  const u64* sb = ain + ((size_t)n * 66 + y) * 68;
  const int* par_row = pa2 + ((size_t)n * 64 + y) * 64;
  int Tx = thr[oc], flip = flp[oc];
  bool anyz = (*flag != 0u);
  u64 rowm = anyz
      ? c2_row<1>(sb, wp + (size_t)oc * 9, wz + (size_t)oc * 9, Tx, flip, lane, par_row)
      : c2_row<0>(sb, wp + (size_t)oc * 9, wz + (size_t)oc * 9, Tx, flip, lane, par_row);
  aout[(((size_t)n * 66 + (y + 1)) * 68 + lane + 1) * 2 + ocw] = rowm;
}

// ---------------------------------------------------------------------------
// conv3/conv4 (CINW=2): VGPR ring + forced vector loads (opaque-zero index),
// selective vmcnt pipelining, prefetch distance 1 px. pa preloaded to SGPRs.
// ---------------------------------------------------------------------------
template <int STRIDE, int IN_HW, int OUT_HW, int RING, int Z>
__device__ __forceinline__ u64 vr_row(const u64* sb2, const u64* wvp_row, const u64* wvz_row,
                                      int Tx, int flip, int lane, const int* par_row, int dz) {
  constexpr int IPW = IN_HW + 4;
  u64 W[18];
#pragma unroll
  for (int t = 0; t < 18; ++t) W[t] = wvp_row[t];
  u64 rowm = 0;

  if (Z) {
    // cold path: direct loads, never taken for this input
    for (int x = 0; x < 32; ++x) {
      int s = 0, z = 0;
      for (int r = 0; r < 3; ++r)
        for (int c = 0; c < 3; ++c)
          for (int w = 0; w < 2; ++w) {
            u64 a = sb2[((size_t)r * IPW + STRIDE * x + c) * 2 + w];
            s += __popcll(a & W[(r * 3 + c) * 2 + w]);
            z += __popcll(a & wvz_row[(r * 3 + c) * 2 + w]);
          }
      int val = 2 * s - par_row[x] + z;
      u64 m_ = __ballot((val ^ flip) >= Tx);
      rowm = (lane == x) ? m_ : rowm;
    }
    return rowm;
  }

  int par[32];
#pragma unroll
  for (int k = 0; k < 32; ++k) par[k] = par_row[k];

  ulonglong2 ring[RING][3];
#define LDCV(SLOT, COL) {                                                        \
  _Pragma("unroll") for (int r_ = 0; r_ < 3; ++r_)                               \
    ring[SLOT][r_] = *((const ulonglong2*)(sb2 + ((size_t)r_ * IPW + (COL)) * 2) + dz); }
#define PIXV(XO, S0, S1, S2) {                                                   \
  int s_ = 0;                                                                    \
  _Pragma("unroll") for (int r_ = 0; r_ < 3; ++r_) {                             \
    ulonglong2 a0 = ring[S0][r_], a1 = ring[S1][r_], a2 = ring[S2][r_];          \
    s_ += __popcll(a0.x & W[(r_ * 3 + 0) * 2]) + __popcll(a0.y & W[(r_ * 3 + 0) * 2 + 1]); \
    s_ += __popcll(a1.x & W[(r_ * 3 + 1) * 2]) + __popcll(a1.y & W[(r_ * 3 + 1) * 2 + 1]); \
    s_ += __popcll(a2.x & W[(r_ * 3 + 2) * 2]) + __popcll(a2.y & W[(r_ * 3 + 2) * 2 + 1]); } \
  int val_ = 2 * s_ - par[XO];                                                   \
  u64 m_ = __ballot((val_ ^ flip) >= Tx);                                        \
  rowm = (lane == (XO)) ? m_ : rowm; }

  LDCV(0, 0) LDCV(1, 1) LDCV(2, 2)
  if (STRIDE == 1) {
#pragma unroll
    for (int x = 0; x < 32; ++x) {
      LDCV((x + 3) & 3, x + 3)
      PIXV(x, x & 3, (x + 1) & 3, (x + 2) & 3)
    }
  } else {
#pragma unroll
    for (int p = 0; p < 32; ++p) {
      LDCV((2 * p + 3) % RING, 2 * p + 3)
      LDCV((2 * p + 4) % RING, 2 * p + 4)
      PIXV(p, (2 * p) % RING, (2 * p + 1) % RING, (2 * p + 2) % RING)
    }
  }
#undef LDCV
#undef PIXV
  return rowm;
}

template <int STRIDE, int IN_HW, int OUT_HW, int OCW, int RPB, int OPAD, int RING>
__global__ __launch_bounds__(64 * OCW * RPB) void bconv_vr(
    const u64* __restrict__ ain, const u64* __restrict__ wp, const u64* __restrict__ wz,
    const u32* __restrict__ flag, const int* __restrict__ thr, const int* __restrict__ flp,
    const int* __restrict__ pa, u64* __restrict__ aout) {
  constexpr int IPW = IN_HW + 4;
  constexpr int BPI = OUT_HW / RPB;
  int tid = threadIdx.x, lane = tid & 63;
  int wv = __builtin_amdgcn_readfirstlane(tid >> 6);
  int ocw = wv % OCW, rblk = wv / OCW;
  int blk = blockIdx.x;
  int y = (blk % BPI) * RPB + rblk;
  int n = blk / BPI;
  int oc = ocw * 64 + lane;
  int dz;
  asm volatile("v_mov_b32 %0, 0" : "=v"(dz));
  const u64* sb2 = ain + ((size_t)n * (IN_HW + 2) + STRIDE * y) * IPW * 2;
  const int* par_row = pa + ((size_t)n * OUT_HW + y) * OUT_HW;
  int Tx = thr[oc], flip = flp[oc];
  bool anyz = (*flag != 0u);
  u64 rowm = anyz
      ? vr_row<STRIDE, IN_HW, OUT_HW, RING, 1>(sb2, wp + (size_t)oc * 18, wz + (size_t)oc * 18,
                                               Tx, flip, lane, par_row, dz)
      : vr_row<STRIDE, IN_HW, OUT_HW, RING, 0>(sb2, wp + (size_t)oc * 18, wz + (size_t)oc * 18,
                                               Tx, flip, lane, par_row, dz);
  if (lane < OUT_HW) {
    if (OPAD)
      aout[(((size_t)n * (OUT_HW + 2) + (y + 1)) * (OUT_HW + 4) + lane + 1) * OCW + ocw] = rowm;
    else
      aout[(((size_t)n * OUT_HW + y) * OUT_HW + lane) * OCW + ocw] = rowm;
  }
}

// ---------------------------------------------------------------------------
// conv5 (unchanged R6): binarized 1x1 + BN + ReLU + partial pool.
// ---------------------------------------------------------------------------
#define NCH5 8
__global__ __launch_bounds__(192) void bconv5_pool(
    const u64* __restrict__ ain, const u64* __restrict__ wp, const u64* __restrict__ wz,
    const u32* __restrict__ flag, const float* __restrict__ inv5, const float* __restrict__ cc5,
    float* __restrict__ partial) {
  int n = blockIdx.x / NCH5, ch = blockIdx.x % NCH5;
  int oc = threadIdx.x;
  u64 W0 = wp[oc * 3], W1 = wp[oc * 3 + 1], W2 = wp[oc * 3 + 2];
  bool anyz = (*flag != 0u);
  float iv = inv5[oc], cb = cc5[oc];
  const u64* sb = ain + ((size_t)n * 1024 + ch * 128) * 3;
  u64 A0, A1, A2, B0, B1, B2, C0, C1, C2;
  float acc = 0.f;
#define LD5(P, a0_, a1_, a2_) { a0_ = sb[(P) * 3]; a1_ = sb[(P) * 3 + 1]; a2_ = sb[(P) * 3 + 2]; }
#define PX5(a0_, a1_, a2_) {                                                   \
  int _pa = __popcll(a0_) + __popcll(a1_) + __popcll(a2_);                     \
  int _s = __popcll(a0_ & W0) + __popcll(a1_ & W1) + __popcll(a2_ & W2);       \
  int _val = 2 * _s - _pa;                                                     \
  if (anyz) _val += __popcll(a0_ & wz[oc * 3]) + __popcll(a1_ & wz[oc * 3 + 1])\
                  + __popcll(a2_ & wz[oc * 3 + 2]);                            \
  float _b = __fadd_rn(__fmul_rn((float)_val, iv), cb);                        \
  acc += fmaxf(_b, 0.f); }
  LD5(0, A0, A1, A2); LD5(1, B0, B1, B2);
  for (int g = 0; g < 42; ++g) {
    LD5(2, C0, C1, C2); PX5(A0, A1, A2);
    LD5(3, A0, A1, A2); PX5(B0, B1, B2);
    LD5(4, B0, B1, B2); PX5(C0, C1, C2);
    sb += 9;
  }
  PX5(A0, A1, A2); PX5(B0, B1, B2);
  partial[((size_t)n * NCH5 + ch) * 192 + oc] = acc;
#undef LD5
#undef PX5
}

// ---------------------------------------------------------------------------
// Fused reduce + head (unchanged R6).
// ---------------------------------------------------------------------------
__global__ __launch_bounds__(192) void head2(
    const float* __restrict__ partial,
    const float* __restrict__ w6, const float* __restrict__ b6,
    const float* __restrict__ fw, const float* __restrict__ fb,
    float* __restrict__ out) {
  __shared__ float pool_s[192];
  __shared__ float h6s[12];
  __shared__ float lgs[12];
  int n = blockIdx.x, t = threadIdx.x;
  float s = 0.f;
#pragma unroll
  for (int ch = 0; ch < NCH5; ++ch) s += partial[((size_t)n * NCH5 + ch) * 192 + t];
  pool_s[t] = s;
  __syncthreads();
  if (t < 12) {
    float a = 0.f;
    for (int c = 0; c < 192; ++c) a += pool_s[c] * w6[t * 192 + c];
    h6s[t] = b6[t] + a * (1.0f / 1024.0f);
  }
  __syncthreads();
  if (t < 12) {
    float s2 = fb[t];
    for (int k = 0; k < 12; ++k) s2 += h6s[k] * fw[t * 12 + k];
    lgs[t] = s2;
  }
  __syncthreads();
  if (t == 0) {
    float mx = -1e30f;
    for (int j = 0; j < 12; ++j) mx = fmaxf(mx, lgs[j]);
    float e[12], se = 0.f;
    for (int j = 0; j < 12; ++j) { e[j] = expf(lgs[j] - mx); se += e[j]; }
    for (int j = 0; j < 12; ++j) out[n * 12 + j] = e[j] / se;
  }
}

// ---------------------------------------------------------------------------
// Launch
// ---------------------------------------------------------------------------
extern "C" void kernel_launch(void* const* d_in, const int* in_sizes, int n_in,
                              void* d_out, int out_size, void* d_ws, size_t ws_size,
                              hipStream_t stream) {
  const float* x   = (const float*)d_in[0];
  const float* w1  = (const float*)d_in[1];
  const float* b1  = (const float*)d_in[2];
  const float* w2  = (const float*)d_in[3];
  const float* w3  = (const float*)d_in[4];
  const float* w4  = (const float*)d_in[5];
  const float* w5  = (const float*)d_in[6];
  const float* w6  = (const float*)d_in[7];
  const float* b6  = (const float*)d_in[8];
  const float* fcw = (const float*)d_in[9];
  const float* fcb = (const float*)d_in[10];
  float* out = (float*)d_out;

  char* ws = (char*)d_ws;
  size_t off = 0;
  auto alloc = [&](size_t bytes) -> void* {
    void* p = ws + off;
    off += (bytes + 255) & ~(size_t)255;
    return p;
  };
  size_t xp_sz = (size_t)128 * 130 * 136 * 4;
  size_t a1_sz = (size_t)128 * 66 * 68 * 1 * 8;
  size_t a2_sz = (size_t)128 * 66 * 68 * 2 * 8;
  size_t a3_sz = (size_t)128 * 34 * 36 * 2 * 8;
  float* xpad = (float*)alloc(xp_sz);
  u64* a1p = (u64*)alloc(a1_sz);
  u64* a2p = (u64*)alloc(a2_sz);
  u64* a3p = (u64*)alloc(a3_sz);
  size_t zero_sz = xp_sz + a1_sz + a2_sz + a3_sz;
  u64* a4p = (u64*)alloc((size_t)128 * 32 * 32 * 3 * 8);
  // pa buffers: pa2 first, pa3/pa4 after (conv2's last-batch over-read of pa2
  // lands in pa3 — allocated, unused).
  int* pa2b = (int*)alloc((size_t)128 * 64 * 64 * 4);
  int* pa3b = (int*)alloc((size_t)128 * 32 * 32 * 4);
  int* pa4b = (int*)alloc((size_t)128 * 32 * 32 * 4);
  float* partial = (float*)alloc((size_t)128 * NCH5 * 192 * 4);
  float* inv1 = (float*)alloc(64 * 4);
  float* cc1  = (float*)alloc(64 * 4);
  float* inv5 = (float*)alloc(192 * 4);
  float* cc5  = (float*)alloc(192 * 4);
  int* thr2 = (int*)alloc(128 * 4); int* flp2 = (int*)alloc(128 * 4);
  int* thr3 = (int*)alloc(128 * 4); int* flp3 = (int*)alloc(128 * 4);
  int* thr4 = (int*)alloc(192 * 4); int* flp4 = (int*)alloc(192 * 4);
  u64* wp2 = (u64*)alloc(128 * 9 * 1 * 8);
  u64* wz2 = (u64*)alloc(128 * 9 * 1 * 8);
  u64* wp3 = (u64*)alloc(128 * 9 * 2 * 8);
  u64* wz3 = (u64*)alloc(128 * 9 * 2 * 8);
  u64* wp4 = (u64*)alloc(192 * 9 * 2 * 8);
  u64* wz4 = (u64*)alloc(192 * 9 * 2 * 8);
  u64* wp5 = (u64*)alloc(192 * 1 * 3 * 8);
  u64* wz5 = (u64*)alloc(192 * 1 * 3 * 8);
  u32* flags = (u32*)alloc(4 * sizeof(u32));
  (void)ws_size; (void)n_in; (void)in_sizes; (void)out_size;

  hipMemsetAsync(xpad, 0, zero_sz, stream);
  hipMemsetAsync(flags, 0, 4 * sizeof(u32), stream);

  PrepArgs pa;
  for (int l = 0; l < 5; ++l) {
    pa.bng[l] = (const float*)d_in[11 + 4 * l + 0];
    pa.bnb[l] = (const float*)d_in[11 + 4 * l + 1];
    pa.bnm[l] = (const float*)d_in[11 + 4 * l + 2];
    pa.bnv[l] = (const float*)d_in[11 + 4 * l + 3];
  }
  pa.inv1 = inv1; pa.cc1 = cc1; pa.inv5 = inv5; pa.cc5 = cc5;
  pa.thr[0] = thr2; pa.flp[0] = flp2;
  pa.thr[1] = thr3; pa.flp[1] = flp3;
  pa.thr[2] = thr4; pa.flp[2] = flp4;
  pa.w[0] = w2; pa.w[1] = w3; pa.w[2] = w4; pa.w[3] = w5;
  pa.wp[0] = wp2; pa.wp[1] = wp3; pa.wp[2] = wp4; pa.wp[3] = wp5;
  pa.wz[0] = wz2; pa.wz[1] = wz3; pa.wz[2] = wz4; pa.wz[3] = wz5;
  pa.flags = flags;
  prep_all<<<32, 256, 0, stream>>>(pa);

  pad_x<<<(128 * 128 * 128) / 256, 256, 0, stream>>>(x, xpad);

  conv1_bin<<<128 * 16, 256, 0, stream>>>(xpad, w1, b1, inv1, cc1, a1p);

  // pa2 from a1p, then conv2 (SGPR batch)
  pa_comp<1, 1, 64, 64><<<128 * 16, 256, 0, stream>>>(a1p, pa2b);
  bconv2<<<128 * 32, 256, 0, stream>>>(a1p, wp2, wz2, flags + 0, thr2, flp2, pa2b, a2p);

  // pa3 from a2p, then conv3 (vring, stride2, ring-of-6, padded out)
  pa_comp<2, 2, 64, 32><<<128 * 4, 256, 0, stream>>>(a2p, pa3b);
  bconv_vr<2, 64, 32, 2, 2, 1, 6><<<128 * 16, 256, 0, stream>>>(
      a2p, wp3, wz3, flags + 1, thr3, flp3, pa3b, a3p);

  // pa4 from a3p, then conv4 (vring, stride1, ring-of-4, dense out)
  pa_comp<2, 1, 32, 32><<<128 * 4, 256, 0, stream>>>(a3p, pa4b);
  bconv_vr<1, 32, 32, 3, 1, 0, 4><<<128 * 32, 192, 0, stream>>>(
      a3p, wp4, wz4, flags + 2, thr4, flp4, pa4b, a4p);

  bconv5_pool<<<128 * NCH5, 192, 0, stream>>>(a4p, wp5, wz5, flags + 3, inv5, cc5, partial);

  head2<<<128, 192, 0, stream>>>(partial, w6, b6, fcw, fcb, out);
}

// Round 8
// 287.607 us; speedup vs baseline: 1.1700x; 1.1700x over previous
//
#include <hip/hip_runtime.h>
#include <cstdint>

using u64 = unsigned long long;
using u32 = unsigned int;

// ---------------------------------------------------------------------------
// Fused prep: BN constants + exact integer thresholds (layers 2-4) + packing.
// ---------------------------------------------------------------------------
struct PrepArgs {
  const float* bng[5]; const float* bnb[5]; const float* bnm[5]; const float* bnv[5];
  float* inv1; float* cc1; float* inv5; float* cc5;
  int* thr[3]; int* flp[3];
  const float* w[4];
  u64* wp[4]; u64* wz[4];
  u32* flags;
};

__global__ __launch_bounds__(256) void prep_all(PrepArgs a) {
  int i = blockIdx.x * 256 + threadIdx.x;
  if (i < 704) {
    const int off[6] = {0, 64, 192, 320, 512, 704};
    int l = 0;
    while (i >= off[l + 1]) ++l;
    int c = i - off[l];
    float iv = __fdiv_rn(a.bng[l][c], __fsqrt_rn(__fadd_rn(a.bnv[l][c], 1e-5f)));
    float cb = __fsub_rn(a.bnb[l][c], __fmul_rn(a.bnm[l][c], iv));
    if (l == 0) { a.inv1[c] = iv; a.cc1[c] = cb; }
    else if (l == 4) { a.inv5[c] = iv; a.cc5[c] = cb; }
    else {
      auto pred = [&](int v_) {
        return __fadd_rn(__fmul_rn((float)v_, iv), cb) > 0.f;
      };
      int Tx, fl;
      if (iv == 0.f) { Tx = pred(0) ? -100000 : 100000; fl = 0; }
      else if (iv > 0.f) {
        if (pred(-2048)) { Tx = -100000; fl = 0; }
        else if (!pred(2048)) { Tx = 100000; fl = 0; }
        else {
          int lo = -2048, hi = 2048;
          while (hi - lo > 1) { int md = (lo + hi) >> 1; if (pred(md)) hi = md; else lo = md; }
          Tx = hi; fl = 0;   // bit = val >= Tx
        }
      } else {
        if (pred(2048)) { Tx = -100000; fl = -1; }
        else if (!pred(-2048)) { Tx = 100000; fl = -1; }
        else {
          int lo = -2048, hi = 2048;
          while (hi - lo > 1) { int md = (lo + hi) >> 1; if (pred(md)) lo = md; else hi = md; }
          Tx = lo ^ -1; fl = -1;   // bit = val <= lo  <=>  (val^-1) >= (~lo)
        }
      }
      a.thr[l - 1][c] = Tx; a.flp[l - 1][c] = fl;
    }
    return;
  }
  int j = i - 704;
  if (j >= 7488) return;
  const int poff[5] = {0, 1152, 3456, 6912, 7488};
  const int ICt[4] = {64, 128, 128, 192};
  const int Kt[4]  = {9, 9, 9, 1};
  const int Wt[4]  = {1, 2, 2, 3};
  int l = 0;
  while (j >= poff[l + 1]) ++l;
  int idx = j - poff[l];
  int W = Wt[l], K = Kt[l], IC = ICt[l];
  int wi = idx % W;
  int rest = idx / W;
  int t = rest % K;
  int oc = rest / K;
  u64 p = 0, z = 0;
  int icbase = wi * 64;
  int nb = IC - icbase; if (nb > 64) nb = 64;
  const float* w = a.w[l];
  for (int b = 0; b < nb; ++b) {
    float f = w[((size_t)oc * IC + (icbase + b)) * K + t];
    if (f > 0.f) p |= (1ull << b);
    else if (f == 0.f) z |= (1ull << b);
  }
  a.wp[l][idx] = p;
  a.wz[l][idx] = z;
  if (z) atomicOr(a.flags + l, 1u);
}

// ---------------------------------------------------------------------------
// Pad fp32 input into [n][130][136].
// ---------------------------------------------------------------------------
__global__ __launch_bounds__(256) void pad_x(const float* __restrict__ x,
                                             float* __restrict__ xpad) {
  int idx = blockIdx.x * 256 + threadIdx.x;
  int c = idx & 127, r = (idx >> 7) & 127, n = idx >> 14;
  xpad[((size_t)n * 130 + r + 1) * 136 + c + 1] = x[idx];
}

// ---------------------------------------------------------------------------
// conv1, lane = pixel: per-lane 3x3 fp32 window in VGPRs (VMEM, one drain),
// loop over 64 channels with uniform scalar weights. Lane accumulates its own
// 64-bit channel word -> one coalesced u64 store per lane.
// Wave = one output row (64 px). waves = 128*64.
// ---------------------------------------------------------------------------
__global__ __launch_bounds__(256) void conv1_px(
    const float* __restrict__ xpad, const float* __restrict__ w1, const float* __restrict__ b1,
    const float* __restrict__ inv1, const float* __restrict__ cc1,
    u64* __restrict__ a1p) {
  int tid = threadIdx.x, lane = tid & 63;
  int wv = __builtin_amdgcn_readfirstlane(tid >> 6);
  int widx = blockIdx.x * 4 + wv;       // 8192
  int y = widx & 63, n = widx >> 6;
  const float* base = xpad + ((size_t)n * 130 + 2 * y) * 136 + 2 * lane;
  float A[9];
#pragma unroll
  for (int r = 0; r < 3; ++r)
#pragma unroll
    for (int c = 0; c < 3; ++c)
      A[r * 3 + c] = base[r * 136 + c];

  u32 wlo = 0, whi = 0;
#pragma unroll 2
  for (int ch = 0; ch < 64; ++ch) {
    float acc = 0.f;
#pragma unroll
    for (int t = 0; t < 9; ++t) acc += A[t] * w1[ch * 9 + t];   // uniform weights
    float h = __fadd_rn(acc, b1[ch]);
    float bnv = __fadd_rn(__fmul_rn(h, inv1[ch]), cc1[ch]);
    u32 b = bnv > 0.f ? 1u : 0u;
    if (ch < 32) wlo |= b << ch;
    else         whi |= b << (ch - 32);
  }
  u64 word = ((u64)whi << 32) | wlo;
  a1p[((size_t)n * 66 + (y + 1)) * 68 + lane + 1] = word;
}

// ---------------------------------------------------------------------------
// Binarized 3x3 conv, lane = pixel. Per-lane window (9*CINW u64) in VGPRs,
// loaded once; loop over oc with uniform scalar weights + int thresholds.
// Per-lane bit accumulation into u32 chunks -> coalesced u32 stores.
// RPW=2 packs 2 rows x 32 px into one wave; NSPLIT splits the oc range
// across waves for occupancy.
// ---------------------------------------------------------------------------
template <int CINW, int COUT, int STRIDE, int IN_HW, int OUT_HW, int RPW, int NSPLIT,
          int OPAD, bool Z>
__device__ __forceinline__ void bconv_body(
    const u64* __restrict__ ain, const u64* __restrict__ wp, const u64* __restrict__ wz,
    const int* __restrict__ thr, const int* __restrict__ flp,
    u64* __restrict__ aout, int widx, int lane) {
  constexpr int IPW = IN_HW + 4;
  constexpr int K = 9 * CINW;
  constexpr int NOC = COUT / NSPLIT;     // oc per wave
  constexpr int NCH = NOC / 32;          // u32 chunks per wave
  constexpr int OWRD = (COUT + 63) / 64; // u64 words per px in output
  constexpr int RG_PER_N = OUT_HW / RPW;
  int split = widx % NSPLIT;
  int rowgrp = widx / NSPLIT;
  int n = rowgrp / RG_PER_N;
  int yg = rowgrp % RG_PER_N;
  int px, r;
  if (RPW == 1) { px = lane; r = 0; }
  else { px = lane & 31; r = lane >> 5; }
  int y = yg * RPW + r;

  const u64* base = ain + (((size_t)n * (IN_HW + 2) + STRIDE * y) * IPW + STRIDE * px) * CINW;
  u64 A[K];
#pragma unroll
  for (int rr = 0; rr < 3; ++rr)
#pragma unroll
    for (int c = 0; c < 3; ++c)
#pragma unroll
      for (int w = 0; w < CINW; ++w)
        A[(rr * 3 + c) * CINW + w] = base[((size_t)rr * IPW + c) * CINW + w];
  int npa = 0;
#pragma unroll
  for (int t = 0; t < K; ++t) npa -= __popcll(A[t]);

  int oc0 = split * NOC;
  size_t orow;
  if (OPAD)
    orow = ((((size_t)n * (OUT_HW + 2) + (y + 1)) * (OUT_HW + 4)) + px + 1) * (OWRD * 2);
  else
    orow = (((size_t)n * OUT_HW + y) * OUT_HW + px) * (OWRD * 2);
  u32* out32 = (u32*)aout;

#pragma unroll
  for (int ch = 0; ch < NCH; ++ch) {
    u32 accw = 0;
#pragma unroll 2
    for (int j = 0; j < 32; ++j) {
      int oc = oc0 + ch * 32 + j;
      const u64* wrow = wp + (size_t)oc * K;    // uniform -> s_load
      int s = 0;
#pragma unroll
      for (int t = 0; t < K; ++t) s += __popcll(A[t] & wrow[t]);
      int val = (s << 1) + npa;                 // 2s - pa
      if (Z) {
        const u64* zr = wz + (size_t)oc * K;
#pragma unroll
        for (int t = 0; t < K; ++t) val += __popcll(A[t] & zr[t]);
      }
      int tt = (val ^ flp[oc]) - thr[oc];
      u32 b = ((u32)~tt) >> 31;                 // 1 iff tt >= 0
      accw |= b << j;
    }
    out32[orow + (u32)(oc0 / 32 + ch)] = accw;
  }
}

template <int CINW, int COUT, int STRIDE, int IN_HW, int OUT_HW, int RPW, int NSPLIT, int OPAD>
__global__ __launch_bounds__(256) void bconv_px(
    const u64* __restrict__ ain, const u64* __restrict__ wp, const u64* __restrict__ wz,
    const u32* __restrict__ flag, const int* __restrict__ thr, const int* __restrict__ flp,
    u64* __restrict__ aout) {
  int tid = threadIdx.x, lane = tid & 63;
  int wv = __builtin_amdgcn_readfirstlane(tid >> 6);
  int widx = blockIdx.x * 4 + wv;
  bool anyz = (*flag != 0u);
  if (anyz)
    bconv_body<CINW, COUT, STRIDE, IN_HW, OUT_HW, RPW, NSPLIT, OPAD, true>(
        ain, wp, wz, thr, flp, aout, widx, lane);
  else
    bconv_body<CINW, COUT, STRIDE, IN_HW, OUT_HW, RPW, NSPLIT, OPAD, false>(
        ain, wp, wz, thr, flp, aout, widx, lane);
}

// ---------------------------------------------------------------------------
// conv5 (binarized 1x1, 192->192) + BN + ReLU + partial pool (R6 version).
// ---------------------------------------------------------------------------
#define NCH5 8
__global__ __launch_bounds__(192) void bconv5_pool(
    const u64* __restrict__ ain, const u64* __restrict__ wp, const u64* __restrict__ wz,
    const u32* __restrict__ flag, const float* __restrict__ inv5, const float* __restrict__ cc5,
    float* __restrict__ partial) {
  int n = blockIdx.x / NCH5, ch = blockIdx.x % NCH5;
  int oc = threadIdx.x;
  u64 W0 = wp[oc * 3], W1 = wp[oc * 3 + 1], W2 = wp[oc * 3 + 2];
  bool anyz = (*flag != 0u);
  float iv = inv5[oc], cb = cc5[oc];
  const u64* sb = ain + ((size_t)n * 1024 + ch * 128) * 3;
  u64 A0, A1, A2, B0, B1, B2, C0, C1, C2;
  float acc = 0.f;
#define LD5(P, a0_, a1_, a2_) { a0_ = sb[(P) * 3]; a1_ = sb[(P) * 3 + 1]; a2_ = sb[(P) * 3 + 2]; }
#define PX5(a0_, a1_, a2_) {                                                   \
  int _pa = __popcll(a0_) + __popcll(a1_) + __popcll(a2_);                     \
  int _s = __popcll(a0_ & W0) + __popcll(a1_ & W1) + __popcll(a2_ & W2);       \
  int _val = 2 * _s - _pa;                                                     \
  if (anyz) _val += __popcll(a0_ & wz[oc * 3]) + __popcll(a1_ & wz[oc * 3 + 1])\
                  + __popcll(a2_ & wz[oc * 3 + 2]);                            \
  float _b = __fadd_rn(__fmul_rn((float)_val, iv), cb);                        \
  acc += fmaxf(_b, 0.f); }
  LD5(0, A0, A1, A2); LD5(1, B0, B1, B2);
  for (int g = 0; g < 42; ++g) {
    LD5(2, C0, C1, C2); PX5(A0, A1, A2);
    LD5(3, A0, A1, A2); PX5(B0, B1, B2);
    LD5(4, B0, B1, B2); PX5(C0, C1, C2);
    sb += 9;
  }
  PX5(A0, A1, A2); PX5(B0, B1, B2);
  partial[((size_t)n * NCH5 + ch) * 192 + oc] = acc;
#undef LD5
#undef PX5
}

// ---------------------------------------------------------------------------
// Fused reduce + head (R6 version).
// ---------------------------------------------------------------------------
__global__ __launch_bounds__(192) void head2(
    const float* __restrict__ partial,
    const float* __restrict__ w6, const float* __restrict__ b6,
    const float* __restrict__ fw, const float* __restrict__ fb,
    float* __restrict__ out) {
  __shared__ float pool_s[192];
  __shared__ float h6s[12];
  __shared__ float lgs[12];
  int n = blockIdx.x, t = threadIdx.x;
  float s = 0.f;
#pragma unroll
  for (int ch = 0; ch < NCH5; ++ch) s += partial[((size_t)n * NCH5 + ch) * 192 + t];
  pool_s[t] = s;
  __syncthreads();
  if (t < 12) {
    float a = 0.f;
    for (int c = 0; c < 192; ++c) a += pool_s[c] * w6[t * 192 + c];
    h6s[t] = b6[t] + a * (1.0f / 1024.0f);
  }
  __syncthreads();
  if (t < 12) {
    float s2 = fb[t];
    for (int k = 0; k < 12; ++k) s2 += h6s[k] * fw[t * 12 + k];
    lgs[t] = s2;
  }
  __syncthreads();
  if (t == 0) {
    float mx = -1e30f;
    for (int j = 0; j < 12; ++j) mx = fmaxf(mx, lgs[j]);
    float e[12], se = 0.f;
    for (int j = 0; j < 12; ++j) { e[j] = expf(lgs[j] - mx); se += e[j]; }
    for (int j = 0; j < 12; ++j) out[n * 12 + j] = e[j] / se;
  }
}

// ---------------------------------------------------------------------------
// Launch
// ---------------------------------------------------------------------------
extern "C" void kernel_launch(void* const* d_in, const int* in_sizes, int n_in,
                              void* d_out, int out_size, void* d_ws, size_t ws_size,
                              hipStream_t stream) {
  const float* x   = (const float*)d_in[0];
  const float* w1  = (const float*)d_in[1];
  const float* b1  = (const float*)d_in[2];
  const float* w2  = (const float*)d_in[3];
  const float* w3  = (const float*)d_in[4];
  const float* w4  = (const float*)d_in[5];
  const float* w5  = (const float*)d_in[6];
  const float* w6  = (const float*)d_in[7];
  const float* b6  = (const float*)d_in[8];
  const float* fcw = (const float*)d_in[9];
  const float* fcb = (const float*)d_in[10];
  float* out = (float*)d_out;

  char* ws = (char*)d_ws;
  size_t off = 0;
  auto alloc = [&](size_t bytes) -> void* {
    void* p = ws + off;
    off += (bytes + 255) & ~(size_t)255;
    return p;
  };
  size_t xp_sz = (size_t)128 * 130 * 136 * 4;
  size_t a1_sz = (size_t)128 * 66 * 68 * 1 * 8;
  size_t a2_sz = (size_t)128 * 66 * 68 * 2 * 8;
  size_t a3_sz = (size_t)128 * 34 * 36 * 2 * 8;
  float* xpad = (float*)alloc(xp_sz);
  u64* a1p = (u64*)alloc(a1_sz);
  u64* a2p = (u64*)alloc(a2_sz);
  u64* a3p = (u64*)alloc(a3_sz);
  size_t zero_sz = xp_sz + a1_sz + a2_sz + a3_sz;
  u64* a4p = (u64*)alloc((size_t)128 * 32 * 32 * 3 * 8);
  float* partial = (float*)alloc((size_t)128 * NCH5 * 192 * 4);
  float* inv1 = (float*)alloc(64 * 4);
  float* cc1  = (float*)alloc(64 * 4);
  float* inv5 = (float*)alloc(192 * 4);
  float* cc5  = (float*)alloc(192 * 4);
  int* thr2 = (int*)alloc(128 * 4); int* flp2 = (int*)alloc(128 * 4);
  int* thr3 = (int*)alloc(128 * 4); int* flp3 = (int*)alloc(128 * 4);
  int* thr4 = (int*)alloc(192 * 4); int* flp4 = (int*)alloc(192 * 4);
  u64* wp2 = (u64*)alloc(128 * 9 * 1 * 8);
  u64* wz2 = (u64*)alloc(128 * 9 * 1 * 8);
  u64* wp3 = (u64*)alloc(128 * 9 * 2 * 8);
  u64* wz3 = (u64*)alloc(128 * 9 * 2 * 8);
  u64* wp4 = (u64*)alloc(192 * 9 * 2 * 8);
  u64* wz4 = (u64*)alloc(192 * 9 * 2 * 8);
  u64* wp5 = (u64*)alloc(192 * 1 * 3 * 8);
  u64* wz5 = (u64*)alloc(192 * 1 * 3 * 8);
  u32* flags = (u32*)alloc(4 * sizeof(u32));
  (void)ws_size; (void)n_in; (void)in_sizes; (void)out_size;

  hipMemsetAsync(xpad, 0, zero_sz, stream);
  hipMemsetAsync(flags, 0, 4 * sizeof(u32), stream);

  PrepArgs pa;
  for (int l = 0; l < 5; ++l) {
    pa.bng[l] = (const float*)d_in[11 + 4 * l + 0];
    pa.bnb[l] = (const float*)d_in[11 + 4 * l + 1];
    pa.bnm[l] = (const float*)d_in[11 + 4 * l + 2];
    pa.bnv[l] = (const float*)d_in[11 + 4 * l + 3];
  }
  pa.inv1 = inv1; pa.cc1 = cc1; pa.inv5 = inv5; pa.cc5 = cc5;
  pa.thr[0] = thr2; pa.flp[0] = flp2;
  pa.thr[1] = thr3; pa.flp[1] = flp3;
  pa.thr[2] = thr4; pa.flp[2] = flp4;
  pa.w[0] = w2; pa.w[1] = w3; pa.w[2] = w4; pa.w[3] = w5;
  pa.wp[0] = wp2; pa.wp[1] = wp3; pa.wp[2] = wp4; pa.wp[3] = wp5;
  pa.wz[0] = wz2; pa.wz[1] = wz3; pa.wz[2] = wz4; pa.wz[3] = wz5;
  pa.flags = flags;
  prep_all<<<32, 256, 0, stream>>>(pa);

  pad_x<<<(128 * 128 * 128) / 256, 256, 0, stream>>>(x, xpad);

  // conv1: lane=pixel, 8192 waves
  conv1_px<<<2048, 256, 0, stream>>>(xpad, w1, b1, inv1, cc1, a1p);

  // conv2: 64ch(1w)->128ch, 64x64, stride1, padded out. 8192 waves.
  bconv_px<1, 128, 1, 64, 64, 1, 1, 1><<<2048, 256, 0, stream>>>(
      a1p, wp2, wz2, flags + 0, thr2, flp2, a2p);

  // conv3: 128ch(2w)->128ch, 64->32, stride2, padded out. 4096 waves (oc split 2).
  bconv_px<2, 128, 2, 64, 32, 2, 2, 1><<<1024, 256, 0, stream>>>(
      a2p, wp3, wz3, flags + 1, thr3, flp3, a3p);

  // conv4: 128ch(2w)->192ch, 32x32, stride1, dense out. 4096 waves (oc split 2).
  bconv_px<2, 192, 1, 32, 32, 2, 2, 0><<<1024, 256, 0, stream>>>(
      a3p, wp4, wz4, flags + 2, thr4, flp4, a4p);

  bconv5_pool<<<128 * NCH5, 192, 0, stream>>>(a4p, wp5, wz5, flags + 3, inv5, cc5, partial);

  head2<<<128, 192, 0, stream>>>(partial, w6, b6, fcw, fcb, out);
}